// Round 14
// baseline (391.474 us; speedup 1.0000x reference)
//
#include <hip/hip_runtime.h>
#include <hip/hip_bf16.h>

// CostVolume stereo head: conv1(1x1)+BN+ReLU (fp32 VALU, split-K, LDS weight
// cache), implicit cost volume, conv3a/conv3b 3x3x3 (bf16 MFMA 16x16x32,
// fp32 accum) + BN + ReLU. conv3a: A staged in LDS (3 kw slabs per kh,kd),
// B from global with DEPTH-2 REGISTER PREFETCH (software pipeline) so L2
// latency hides under the previous groups' MFMAs. conv3b: r11-proven.
// B=1, H=48, W=160, CIN=1024, CF=64, D=48.

#define HH   48
#define WW   160
#define DDEP 48
#define CIN  1024
#define NPX  (HH*WW)   // 7680
#define KSPL 16        // conv1 split-K factor

typedef unsigned short u16;
typedef unsigned int   u32;
typedef __attribute__((ext_vector_type(8))) short bf16x8;
typedef __attribute__((ext_vector_type(4))) float f32x4;
typedef __attribute__((ext_vector_type(4))) u32   u32x4;
typedef __attribute__((ext_vector_type(2))) u32   u32x2;

__device__ __forceinline__ u16 f2bf(float f) {
    u32 u = __builtin_bit_cast(u32, f);
    u32 r = u + 0x7FFFu + ((u >> 16) & 1u);   // RNE
    return (u16)(r >> 16);
}

// ---------------------------------------------------------------------------
// Prep: weights -> bf16 in MFMA-friendly layouts + fused BN constants.
// wa[tap][o][i]           tap = kd*9+kh*3+kw, i in [0,128)   (27*64*128)
// wb[(kd*3+kh)][o][kw*64+i]  i in [0,64)                      (9*64*192)
// bnc[0..63]=s3a  [64..127]=t3a  [128..191]=s3b  [192..255]=t3b
// ---------------------------------------------------------------------------
__global__ __launch_bounds__(256) void k_prep(
    const float* __restrict__ c3a, const float* __restrict__ c3b,
    const float* __restrict__ cb3a, const float* __restrict__ g3a,
    const float* __restrict__ b3a,  const float* __restrict__ m3a,
    const float* __restrict__ v3a,
    const float* __restrict__ cb3b, const float* __restrict__ g3b,
    const float* __restrict__ b3b,  const float* __restrict__ m3b,
    const float* __restrict__ v3b,
    u16* __restrict__ wa, u16* __restrict__ wb, float* __restrict__ bnc)
{
    int tid = blockIdx.x*256 + threadIdx.x;
    if (tid < 221184) {
        int i = tid & 127, o = (tid >> 7) & 63, tap = tid >> 13;
        wa[tid] = f2bf(c3a[(o*128 + i)*27 + tap]);
    } else {
        int t2 = tid - 221184;
        if (t2 < 110592) {
            int i = t2 & 63;
            int kw = (t2 >> 6) % 3;
            int rest = t2 / 192;
            int o = rest & 63, kdkh = rest >> 6;
            wb[t2] = f2bf(c3b[(o*64 + i)*27 + (kdkh/3)*9 + (kdkh%3)*3 + kw]);
        }
    }
    if (tid < 64) {
        float s = g3a[tid] * rsqrtf(v3a[tid] + 1e-5f);
        bnc[tid]      = s;
        bnc[64 + tid] = (cb3a[tid] - m3a[tid])*s + b3a[tid];
    } else if (tid < 128) {
        int o = tid - 64;
        float s = g3b[o] * rsqrtf(v3b[o] + 1e-5f);
        bnc[128 + o] = s;
        bnc[192 + o] = (cb3b[o] - m3b[o])*s + b3b[o];
    }
}

// ---------------------------------------------------------------------------
// conv1 (1x1) split-K partial, fp32 VALU. W chunk (64o x 64i, 16 KB) staged
// in LDS once per block; inner loop reads weights via LDS BROADCAST.
// Lane = pixel. Partials -> P[s][img][px][o] (in d_out).
// grid (120, 2, 16), block 256.
// ---------------------------------------------------------------------------
__global__ __launch_bounds__(256) void k_conv1(
    const float* __restrict__ left, const float* __restrict__ right,
    const float* __restrict__ w1, float* __restrict__ P)
{
    __shared__ float Ws[4096];   // [64 o][64 i]
    const int img = blockIdx.y;
    const int s   = blockIdx.z;
    const float* x = img ? right : left;
    const int tid = threadIdx.x;
    const int px = blockIdx.x*64 + (tid & 63);
    const int o0 = (tid >> 6)*16;   // wave-uniform
    const int ibase = s*(CIN/KSPL);

    #pragma unroll
    for (int q = 0; q < 4; ++q) {
        int idx = q*256 + tid;             // 1024 chunks of 4 floats
        int o = idx >> 4, ii = (idx & 15)*4;
        *(f32x4*)(Ws + o*64 + ii) =
            *(const f32x4*)(w1 + (size_t)o*CIN + ibase + ii);
    }
    __syncthreads();

    float acc[16];
    #pragma unroll
    for (int oo = 0; oo < 16; ++oo) acc[oo] = 0.f;

    for (int it = 0; it < CIN/KSPL; it += 4) {
        const int i = ibase + it;
        float x0 = x[(i+0)*NPX + px];
        float x1 = x[(i+1)*NPX + px];
        float x2 = x[(i+2)*NPX + px];
        float x3 = x[(i+3)*NPX + px];
        #pragma unroll
        for (int oo = 0; oo < 16; ++oo) {
            const float4 wv4 = *(const float4*)(Ws + (o0+oo)*64 + it);
            acc[oo] = fmaf(wv4.w, x3, fmaf(wv4.z, x2,
                      fmaf(wv4.y, x1, fmaf(wv4.x, x0, acc[oo]))));
        }
    }
    float* dst = P + ((size_t)(s*2 + img)*NPX + px)*64 + o0;
    #pragma unroll
    for (int q = 0; q < 4; ++q)
        *(f32x4*)(dst + q*4) = *(const f32x4*)(acc + q*4);
}

// ---------------------------------------------------------------------------
// conv1 reduce: sum 16 K-chunk partials (stride 2*NPX*64) + bias + BN + ReLU
// -> bf16 LRb2 in CHUNKED layout [img][h][c=o/8][w][8]. grid (960), 256.
// ---------------------------------------------------------------------------
__global__ __launch_bounds__(256) void k_conv1_reduce(
    const float* __restrict__ P,
    const float* __restrict__ b1,
    const float* __restrict__ g,  const float* __restrict__ bb,
    const float* __restrict__ m,  const float* __restrict__ v,
    u16* __restrict__ LRb)
{
    const int tid = blockIdx.x*256 + threadIdx.x;
    const int f = tid*4;                      // flat [img][px][o], o%4==0
    f32x4 acc = *(const f32x4*)(P + f);
    #pragma unroll
    for (int s = 1; s < KSPL; ++s)
        acc += *(const f32x4*)(P + (size_t)(s*2)*(NPX*64) + f);
    const int o0 = f & 63;
    const int px = f >> 6;
    const int img = px / NPX, pxl = px - img*NPX;
    const int h = pxl / WW, w = pxl - h*WW;
    u16 res[4];
    #pragma unroll
    for (int r = 0; r < 4; ++r) {
        int o = o0 + r;
        float sc = g[o] * rsqrtf(v[o] + 1e-5f);
        float val = (acc[r] + b1[o] - m[o])*sc + bb[o];
        res[r] = f2bf(val > 0.f ? val : 0.f);
    }
    u16* dst = LRb + (size_t)img*491520 + h*10240 + (o0 >> 3)*1280
                   + w*8 + (o0 & 7);
    *(u32x2*)dst = *(const u32x2*)res;
}

// ---------------------------------------------------------------------------
// conv3a helpers: group g in [0,12) = (kw = g>>2, ic = g&3). ic<2 -> L, else R.
// ---------------------------------------------------------------------------
__device__ __forceinline__ void cv3a_issue(
    bf16x8 (&Pb)[5], int g, int dp, bool dok, int wcol, int l4,
    const u16* __restrict__ lrow, const u16* __restrict__ rrow)
{
    const int kw = g >> 2, ic = g & 3;
    const u16* base = ((ic < 2) ? lrow : rrow)
                    + (size_t)((ic & 1)*4 + l4)*1280;
    #pragma unroll
    for (int nf = 0; nf < 5; ++nf) {
        int wp = wcol + nf*16 + kw - 1;
        bool vv = dok && (wp >= 0) && (wp < WW) && (wp >= dp);
        int ofs = (vv ? ((ic < 2) ? wp : (wp - dp)) : 0)*8;
        Pb[nf] = *(const bf16x8*)(base + ofs);
    }
}

__device__ __forceinline__ void cv3a_consume(
    f32x4 (&acc)[4][5], const bf16x8 (&Pb)[5], const u16* __restrict__ Aw,
    int g, int dp, bool dok, int wcol, int l4, int l15)
{
    const int kw = g >> 2, ic = g & 3;
    const bf16x8 bzero = {0,0,0,0,0,0,0,0};
    const u16* awk = Aw + kw*8704;
    const int kcolA = ic*32 + 8*l4;
    bf16x8 a0 = *(const bf16x8*)(awk + ( 0 + l15)*136 + kcolA);
    bf16x8 a1 = *(const bf16x8*)(awk + (16 + l15)*136 + kcolA);
    bf16x8 a2 = *(const bf16x8*)(awk + (32 + l15)*136 + kcolA);
    bf16x8 a3 = *(const bf16x8*)(awk + (48 + l15)*136 + kcolA);
    #pragma unroll
    for (int nf = 0; nf < 5; ++nf) {
        int wp = wcol + nf*16 + kw - 1;
        bool vv = dok && (wp >= 0) && (wp < WW) && (wp >= dp);
        bf16x8 b = vv ? Pb[nf] : bzero;
        acc[0][nf] = __builtin_amdgcn_mfma_f32_16x16x32_bf16(a0, b, acc[0][nf], 0, 0, 0);
        acc[1][nf] = __builtin_amdgcn_mfma_f32_16x16x32_bf16(a1, b, acc[1][nf], 0, 0, 0);
        acc[2][nf] = __builtin_amdgcn_mfma_f32_16x16x32_bf16(a2, b, acc[2][nf], 0, 0, 0);
        acc[3][nf] = __builtin_amdgcn_mfma_f32_16x16x32_bf16(a3, b, acc[3][nf], 0, 0, 0);
    }
}

// ---------------------------------------------------------------------------
// conv3a: implicit cost-volume 3x3x3 conv, bf16 MFMA. Block = (h, d-pair),
// 4 waves: wave -> (dd = wv>>1, wbase = (wv&1)*80). M=64 o x N=80 per wave.
// Per (kh,kd): stage 3 kw weight slabs [3][64][136] (51 KB). B from GLOBAL
// (chunked LRb2 layout) with DEPTH-2 register prefetch: groups g=0..11,
// P0/P1 ping-pong; G0,G1 issued BEFORE the barriers (loads cross barriers),
// step g consumes then re-issues for g+2 -> each load covered by ~2 MFMA
// groups. Epilogue: BN+ReLU -> bf16 u32-pair stores to y2[d][h][c][w][8].
// grid (48, 24), block 256. LDS 52.2 KB; VGPR capped for 3 waves/SIMD.
// ---------------------------------------------------------------------------
__global__ __launch_bounds__(256, 3) void k_conv3a(
    const u16* __restrict__ LRb, const u16* __restrict__ wa,
    const float* __restrict__ bnc, u16* __restrict__ yt)
{
    __shared__ u16 Aw[26112];   // [3 kw][64][136]  (68 dw pitch)

    const int h  = blockIdx.x;
    const int d0 = blockIdx.y*2;
    const int tid = threadIdx.x;
    const int l  = tid & 63;
    const int wv = tid >> 6;
    const int dd = wv >> 1;
    const int wbase = (wv & 1)*80;
    const int l15 = l & 15, l4 = l >> 4;
    const int wcol = wbase + l15;

    f32x4 acc[4][5];
    #pragma unroll
    for (int a = 0; a < 4; ++a)
        #pragma unroll
        for (int b = 0; b < 5; ++b)
            acc[a][b] = (f32x4){0.f,0.f,0.f,0.f};

    for (int kh = 0; kh < 3; ++kh) {
        int hp = h + kh - 1;
        if (hp < 0 || hp >= HH) continue;      // block-uniform
        const u16* lrow = LRb + (size_t)hp*10240;
        const u16* rrow = LRb + 491520 + (size_t)hp*10240;
        for (int kd = 0; kd < 3; ++kd) {
            const int dp = d0 + dd + kd - 1;   // per-wave
            const bool dok = (dp >= 0) && (dp < DDEP);

            bf16x8 P0[5], P1[5];
            cv3a_issue(P0, 0, dp, dok, wcol, l4, lrow, rrow);
            cv3a_issue(P1, 1, dp, dok, wcol, l4, lrow, rrow);

            __syncthreads();                   // prev interval's Aw reads done
            {
                // 3 kw slabs contiguous in wa: 24576 u16 = 3072 x 8-chunks
                const u16* as = wa + (size_t)(kd*9 + kh*3)*8192;
                #pragma unroll
                for (int q = 0; q < 12; ++q) {
                    int idx = q*256 + tid;
                    int t = idx >> 10;          // kw slab 0..2
                    int e = idx & 1023;         // chunk within slab
                    int o = e >> 4, ii = (e & 15)*8;
                    *(u32x4*)(Aw + t*8704 + o*136 + ii) =
                        *(const u32x4*)(as + (size_t)idx*8);
                }
            }
            __syncthreads();                   // Aw visible

            #pragma unroll
            for (int g = 0; g < 12; ++g) {
                if ((g & 1) == 0) {
                    cv3a_consume(acc, P0, Aw, g, dp, dok, wcol, l4, l15);
                    if (g + 2 < 12)
                        cv3a_issue(P0, g + 2, dp, dok, wcol, l4, lrow, rrow);
                } else {
                    cv3a_consume(acc, P1, Aw, g, dp, dok, wcol, l4, l15);
                    if (g + 2 < 12)
                        cv3a_issue(P1, g + 2, dp, dok, wcol, l4, lrow, rrow);
                }
            }
        }
    }

    // epilogue: BN+ReLU, direct u32 (bf16-pair) stores to y2[d][h][c][w][8]
    float sc[4][4], sh[4][4];
    #pragma unroll
    for (int mf = 0; mf < 4; ++mf)
        #pragma unroll
        for (int r = 0; r < 4; ++r) {
            int o = mf*16 + 4*l4 + r;
            sc[mf][r] = bnc[o];
            sh[mf][r] = bnc[64 + o];
        }
    const int dy = d0 + dd;
    u16* rowb = yt + (size_t)(dy*HH + h)*10240;
    #pragma unroll
    for (int mf = 0; mf < 4; ++mf)
        #pragma unroll
        for (int nf = 0; nf < 5; ++nf) {
            const int w = wbase + nf*16 + l15;
            #pragma unroll
            for (int rp = 0; rp < 2; ++rp) {
                int o_lo = mf*16 + 4*l4 + rp*2;
                float v0 = acc[mf][nf][rp*2]  *sc[mf][rp*2]   + sh[mf][rp*2];
                float v1 = acc[mf][nf][rp*2+1]*sc[mf][rp*2+1] + sh[mf][rp*2+1];
                v0 = v0 > 0.f ? v0 : 0.f;
                v1 = v1 > 0.f ? v1 : 0.f;
                u32 pk = (u32)f2bf(v0) | ((u32)f2bf(v1) << 16);
                *(u32*)(rowb + (o_lo >> 3)*1280 + w*8 + (o_lo & 7)) = pk;
            }
        }
}

// ---------------------------------------------------------------------------
// conv3b: 3x3x3 conv on y2[d][h][c][w][8], bf16 MFMA, fp32 out + BN + ReLU.
// EXACT r11 version (proven, ~40us). Block = (h, d-pair), 4 waves. B from
// GLOBAL (256B-contiguous per 16-lane phase); LDS = weight slab only.
// grid (48,24), block 256.
// ---------------------------------------------------------------------------
__global__ __launch_bounds__(256) void k_conv3b(
    const u16* __restrict__ yt, const u16* __restrict__ wb,
    const float* __restrict__ bnc, float* __restrict__ outp)
{
    __shared__ u16 A2[12800];   // [64][200] (100 dw pitch, %32==4)

    const int h  = blockIdx.x;
    const int d0 = blockIdx.y*2;
    const int tid = threadIdx.x;
    const int l  = tid & 63;
    const int wv = tid >> 6;
    const int dd = wv >> 1;
    const int wbase = (wv & 1)*80;
    const int l15 = l & 15, l4 = l >> 4;
    const int wcol = wbase + l15;
    const bf16x8 bzero = {0,0,0,0,0,0,0,0};

    f32x4 acc[4][5];
    #pragma unroll
    for (int a = 0; a < 4; ++a)
        #pragma unroll
        for (int b = 0; b < 5; ++b)
            acc[a][b] = (f32x4){0.f,0.f,0.f,0.f};

    for (int kh = 0; kh < 3; ++kh) {
        int hp = h + kh - 1;
        if (hp < 0 || hp >= HH) continue;   // block-uniform
        for (int kd = 0; kd < 3; ++kd) {
            __syncthreads();                // prior A2 reads done
            {
                const u16* as = wb + (size_t)(kd*3 + kh)*12288;
                #pragma unroll
                for (int q = 0; q < 6; ++q) {
                    int idx = q*256 + tid;
                    int o = idx/24;
                    int cc = (idx - o*24)*8;
                    *(u32x4*)(A2 + o*200 + cc) = *(const u32x4*)(as + (size_t)idx*8);
                }
            }
            __syncthreads();

            const int dpw = d0 + dd + kd - 1;
            const bool dok = (dpw >= 0) && (dpw < DDEP);
            const int dc = min(max(dpw, 0), DDEP-1);
            const u16* yrow = yt + ((size_t)((dc*HH + hp)*8) + l4)*1280;
            for (int kw = 0; kw < 3; ++kw) {
                int gofs[5]; bool val[5];
                #pragma unroll
                for (int nf = 0; nf < 5; ++nf) {
                    int wp = wcol + nf*16 + kw - 1;
                    bool vv = dok && (wp >= 0) && (wp < WW);
                    val[nf]  = vv;
                    gofs[nf] = (vv ? wp : 0)*8;
                }
                #pragma unroll
                for (int ic = 0; ic < 2; ++ic) {
                    const int kcolA = kw*64 + ic*32 + 8*l4;
                    bf16x8 a0 = *(const bf16x8*)(A2 + ( 0 + l15)*200 + kcolA);
                    bf16x8 a1 = *(const bf16x8*)(A2 + (16 + l15)*200 + kcolA);
                    bf16x8 a2 = *(const bf16x8*)(A2 + (32 + l15)*200 + kcolA);
                    bf16x8 a3 = *(const bf16x8*)(A2 + (48 + l15)*200 + kcolA);
                    const u16* yc = yrow + ic*5120;
                    #pragma unroll
                    for (int nf = 0; nf < 5; ++nf) {
                        bf16x8 b = *(const bf16x8*)(yc + gofs[nf]);
                        b = val[nf] ? b : bzero;
                        acc[0][nf] = __builtin_amdgcn_mfma_f32_16x16x32_bf16(a0, b, acc[0][nf], 0, 0, 0);
                        acc[1][nf] = __builtin_amdgcn_mfma_f32_16x16x32_bf16(a1, b, acc[1][nf], 0, 0, 0);
                        acc[2][nf] = __builtin_amdgcn_mfma_f32_16x16x32_bf16(a2, b, acc[2][nf], 0, 0, 0);
                        acc[3][nf] = __builtin_amdgcn_mfma_f32_16x16x32_bf16(a3, b, acc[3][nf], 0, 0, 0);
                    }
                }
            }
        }
    }

    // epilogue: fp32 out[(o*48+d)*48*160 + h*160 + w], coalesced along w
    const int dout = d0 + dd;
    #pragma unroll
    for (int mf = 0; mf < 4; ++mf)
        #pragma unroll
        for (int r = 0; r < 4; ++r) {
            int o = mf*16 + 4*l4 + r;
            float s = bnc[128 + o], t = bnc[192 + o];
            size_t base = ((size_t)(o*DDEP + dout)*HH + h)*WW + wbase;
            #pragma unroll
            for (int nf = 0; nf < 5; ++nf) {
                float vv = acc[mf][nf][r]*s + t;
                outp[base + nf*16 + l15] = vv > 0.f ? vv : 0.f;
            }
        }
}

// ---------------------------------------------------------------------------
extern "C" void kernel_launch(void* const* d_in, const int* in_sizes, int n_in,
                              void* d_out, int out_size, void* d_ws, size_t ws_size,
                              hipStream_t stream)
{
    const float* left  = (const float*)d_in[0];
    const float* right = (const float*)d_in[1];
    const float* w1    = (const float*)d_in[2];
    const float* b1    = (const float*)d_in[3];
    const float* g1    = (const float*)d_in[4];
    const float* bb1   = (const float*)d_in[5];
    const float* m1    = (const float*)d_in[6];
    const float* v1    = (const float*)d_in[7];
    const float* c3a   = (const float*)d_in[8];
    const float* cb3a  = (const float*)d_in[9];
    const float* g3a   = (const float*)d_in[10];
    const float* b3a   = (const float*)d_in[11];
    const float* m3a   = (const float*)d_in[12];
    const float* v3a   = (const float*)d_in[13];
    const float* c3b   = (const float*)d_in[14];
    const float* cb3b  = (const float*)d_in[15];
    const float* g3b   = (const float*)d_in[16];
    const float* b3b   = (const float*)d_in[17];
    const float* m3b   = (const float*)d_in[18];
    const float* v3b   = (const float*)d_in[19];

    // workspace layout (bytes, all 16B-aligned):
    //   LRb2 bf16 [2][48][8][160][8]     : 1,966,080   (chunked conv1 output)
    //   wa   bf16 [27][64][128]          :   442,368
    //   wb   bf16 [9][64][192]           :   221,184
    //   bnc  f32  [256]                  :     1,024
    //   yt   bf16 [48][48][8][160][8]    : 47,185,920  (chunked y2 layout)
    // conv1 split-K partials (fp32, 62.9 MB) live in d_out (94 MB fp32),
    // which conv3b fully overwrites afterwards.
    char* ws = (char*)d_ws;
    u16*   LRb = (u16*)ws;
    u16*   wa  = (u16*)(ws + 1966080);
    u16*   wb  = (u16*)(ws + 1966080 + 442368);
    float* bnc = (float*)(ws + 1966080 + 442368 + 221184);
    u16*   yt  = (u16*)(ws + 1966080 + 442368 + 221184 + 1024);
    if (ws_size < 49816576) return;   // visible failure (all-zero out) rather than corruption

    float* P = (float*)d_out;         // [KSPL][2][7680][64] fp32 partials

    k_prep<<<dim3(1296), dim3(256), 0, stream>>>(
        c3a, c3b, cb3a, g3a, b3a, m3a, v3a, cb3b, g3b, b3b, m3b, v3b, wa, wb, bnc);
    k_conv1<<<dim3(120, 2, KSPL), dim3(256), 0, stream>>>(
        left, right, w1, P);
    k_conv1_reduce<<<dim3(960), dim3(256), 0, stream>>>(
        P, b1, g1, bb1, m1, v1, LRb);
    k_conv3a<<<dim3(48, 24), dim3(256), 0, stream>>>(LRb, wa, bnc, yt);
    k_conv3b<<<dim3(48, 24), dim3(256), 0, stream>>>(yt, wb, bnc, (float*)d_out);
}

// Round 15
// 320.485 us; speedup vs baseline: 1.2215x; 1.2215x over previous
//
#include <hip/hip_runtime.h>
#include <hip/hip_bf16.h>

// CostVolume stereo head — best-of assembly (r15):
//   conv1: split-K 16, LDS weight cache (r14-proven)
//   conv3a: r11-proven LDS structure (Lt/Rt + Aw staged, 2 barriers/tap),
//           chunked y2 output
//   conv3b: r11-proven (B from global, chunked layout, tiny LDS)
// B=1, H=48, W=160, CIN=1024, CF=64, D=48.

#define HH   48
#define WW   160
#define DDEP 48
#define CIN  1024
#define NPX  (HH*WW)   // 7680
#define KSPL 16        // conv1 split-K factor

typedef unsigned short u16;
typedef unsigned int   u32;
typedef __attribute__((ext_vector_type(8))) short bf16x8;
typedef __attribute__((ext_vector_type(4))) float f32x4;
typedef __attribute__((ext_vector_type(4))) u32   u32x4;
typedef __attribute__((ext_vector_type(2))) u32   u32x2;

__device__ __forceinline__ u16 f2bf(float f) {
    u32 u = __builtin_bit_cast(u32, f);
    u32 r = u + 0x7FFFu + ((u >> 16) & 1u);   // RNE
    return (u16)(r >> 16);
}

// ---------------------------------------------------------------------------
// Prep: weights -> bf16 in MFMA-friendly layouts + fused BN constants.
// wa[tap][o][i]           tap = kd*9+kh*3+kw, i in [0,128)   (27*64*128)
// wb[(kd*3+kh)][o][kw*64+i]  i in [0,64)                      (9*64*192)
// bnc[0..63]=s3a  [64..127]=t3a  [128..191]=s3b  [192..255]=t3b
// ---------------------------------------------------------------------------
__global__ __launch_bounds__(256) void k_prep(
    const float* __restrict__ c3a, const float* __restrict__ c3b,
    const float* __restrict__ cb3a, const float* __restrict__ g3a,
    const float* __restrict__ b3a,  const float* __restrict__ m3a,
    const float* __restrict__ v3a,
    const float* __restrict__ cb3b, const float* __restrict__ g3b,
    const float* __restrict__ b3b,  const float* __restrict__ m3b,
    const float* __restrict__ v3b,
    u16* __restrict__ wa, u16* __restrict__ wb, float* __restrict__ bnc)
{
    int tid = blockIdx.x*256 + threadIdx.x;
    if (tid < 221184) {
        int i = tid & 127, o = (tid >> 7) & 63, tap = tid >> 13;
        wa[tid] = f2bf(c3a[(o*128 + i)*27 + tap]);
    } else {
        int t2 = tid - 221184;
        if (t2 < 110592) {
            int i = t2 & 63;
            int kw = (t2 >> 6) % 3;
            int rest = t2 / 192;
            int o = rest & 63, kdkh = rest >> 6;
            wb[t2] = f2bf(c3b[(o*64 + i)*27 + (kdkh/3)*9 + (kdkh%3)*3 + kw]);
        }
    }
    if (tid < 64) {
        float s = g3a[tid] * rsqrtf(v3a[tid] + 1e-5f);
        bnc[tid]      = s;
        bnc[64 + tid] = (cb3a[tid] - m3a[tid])*s + b3a[tid];
    } else if (tid < 128) {
        int o = tid - 64;
        float s = g3b[o] * rsqrtf(v3b[o] + 1e-5f);
        bnc[128 + o] = s;
        bnc[192 + o] = (cb3b[o] - m3b[o])*s + b3b[o];
    }
}

// ---------------------------------------------------------------------------
// conv1 (1x1) split-K partial, fp32 VALU. W chunk (64o x 64i, 16 KB) staged
// in LDS once per block; inner loop reads weights via LDS BROADCAST.
// Lane = pixel. Partials -> P[s][img][px][o] (in d_out).
// grid (120, 2, 16), block 256.
// ---------------------------------------------------------------------------
__global__ __launch_bounds__(256) void k_conv1(
    const float* __restrict__ left, const float* __restrict__ right,
    const float* __restrict__ w1, float* __restrict__ P)
{
    __shared__ float Ws[4096];   // [64 o][64 i]
    const int img = blockIdx.y;
    const int s   = blockIdx.z;
    const float* x = img ? right : left;
    const int tid = threadIdx.x;
    const int px = blockIdx.x*64 + (tid & 63);
    const int o0 = (tid >> 6)*16;   // wave-uniform
    const int ibase = s*(CIN/KSPL);

    #pragma unroll
    for (int q = 0; q < 4; ++q) {
        int idx = q*256 + tid;             // 1024 chunks of 4 floats
        int o = idx >> 4, ii = (idx & 15)*4;
        *(f32x4*)(Ws + o*64 + ii) =
            *(const f32x4*)(w1 + (size_t)o*CIN + ibase + ii);
    }
    __syncthreads();

    float acc[16];
    #pragma unroll
    for (int oo = 0; oo < 16; ++oo) acc[oo] = 0.f;

    for (int it = 0; it < CIN/KSPL; it += 4) {
        const int i = ibase + it;
        float x0 = x[(i+0)*NPX + px];
        float x1 = x[(i+1)*NPX + px];
        float x2 = x[(i+2)*NPX + px];
        float x3 = x[(i+3)*NPX + px];
        #pragma unroll
        for (int oo = 0; oo < 16; ++oo) {
            const float4 wv4 = *(const float4*)(Ws + (o0+oo)*64 + it);
            acc[oo] = fmaf(wv4.w, x3, fmaf(wv4.z, x2,
                      fmaf(wv4.y, x1, fmaf(wv4.x, x0, acc[oo]))));
        }
    }
    float* dst = P + ((size_t)(s*2 + img)*NPX + px)*64 + o0;
    #pragma unroll
    for (int q = 0; q < 4; ++q)
        *(f32x4*)(dst + q*4) = *(const f32x4*)(acc + q*4);
}

// ---------------------------------------------------------------------------
// conv1 reduce: sum 16 K-chunk partials (stride 2*NPX*64) + bias + BN + ReLU
// -> bf16 LRb2 in CHUNKED layout [img][h][c=o/8][w][8]. grid (960), 256.
// ---------------------------------------------------------------------------
__global__ __launch_bounds__(256) void k_conv1_reduce(
    const float* __restrict__ P,
    const float* __restrict__ b1,
    const float* __restrict__ g,  const float* __restrict__ bb,
    const float* __restrict__ m,  const float* __restrict__ v,
    u16* __restrict__ LRb)
{
    const int tid = blockIdx.x*256 + threadIdx.x;
    const int f = tid*4;                      // flat [img][px][o], o%4==0
    f32x4 acc = *(const f32x4*)(P + f);
    #pragma unroll
    for (int s = 1; s < KSPL; ++s)
        acc += *(const f32x4*)(P + (size_t)(s*2)*(NPX*64) + f);
    const int o0 = f & 63;
    const int px = f >> 6;
    const int img = px / NPX, pxl = px - img*NPX;
    const int h = pxl / WW, w = pxl - h*WW;
    u16 res[4];
    #pragma unroll
    for (int r = 0; r < 4; ++r) {
        int o = o0 + r;
        float sc = g[o] * rsqrtf(v[o] + 1e-5f);
        float val = (acc[r] + b1[o] - m[o])*sc + bb[o];
        res[r] = f2bf(val > 0.f ? val : 0.f);
    }
    u16* dst = LRb + (size_t)img*491520 + h*10240 + (o0 >> 3)*1280
                   + w*8 + (o0 & 7);
    *(u32x2*)dst = *(const u32x2*)res;
}

// ---------------------------------------------------------------------------
// conv3a: implicit cost-volume 3x3x3 conv, bf16 MFMA. Block = (h, d-pair),
// 4 waves: wave -> (dd = wv>>1, wbase = (wv&1)*80). M=64 o x N=80 per wave.
// PROVEN r11 structure (L/R staged per kh from chunked LRb2, Aw staged per
// tap, 2 barriers/tap). Epilogue: BN+ReLU -> bf16, LDS transpose -> chunked
// y2[d][h][c=o/8][w][8]. grid (48, 24), block 256. LDS 63.5 KB.
// ---------------------------------------------------------------------------
__global__ __launch_bounds__(256) void k_conv3a(
    const u16* __restrict__ LRb, const u16* __restrict__ wa,
    const float* __restrict__ bnc, u16* __restrict__ yt)
{
    __shared__ u16 sm[31744];
    u16* Lt = sm;            // [160][72]  (36 dw pitch, %32==4)
    u16* Rt = sm + 11520;    // [160][72]
    u16* Aw = sm + 23040;    // [64][136]  (68 dw pitch, %32==4)

    const int h  = blockIdx.x;
    const int d0 = blockIdx.y*2;
    const int tid = threadIdx.x;
    const int l  = tid & 63;
    const int wv = tid >> 6;
    const int dd = wv >> 1;
    const int wbase = (wv & 1)*80;
    const int l15 = l & 15, l4 = l >> 4;
    const int wcol = wbase + l15;
    const bf16x8 bzero = {0,0,0,0,0,0,0,0};

    f32x4 acc[4][5];
    #pragma unroll
    for (int a = 0; a < 4; ++a)
        #pragma unroll
        for (int b = 0; b < 5; ++b)
            acc[a][b] = (f32x4){0.f,0.f,0.f,0.f};

    for (int kh = 0; kh < 3; ++kh) {
        int hp = h + kh - 1;
        if (hp < 0 || hp >= HH) continue;      // block-uniform
        __syncthreads();                       // prev kh reads done
        {
            // stage from chunked LRb2 [img][h][c][w][8]: rows are 10240 u16
            // contiguous -> linear copy into [w][72] padded tiles
            const u16* ls = LRb + (size_t)hp*10240;
            const u16* rs = LRb + 491520 + (size_t)hp*10240;
            #pragma unroll
            for (int gq = 0; gq < 5; ++gq) {
                int eb = (gq*256 + tid)*8;     // element offset in row
                int c = eb / 1280, rem = eb - c*1280;
                int w = rem >> 3;              // w within chunk row
                // dest: Lt[w][c*8 .. c*8+8)
                u32x4 va = *(const u32x4*)(ls + eb);
                u32x4 vb = *(const u32x4*)(rs + eb);
                *(u32x4*)(Lt + w*72 + c*8) = va;
                *(u32x4*)(Rt + w*72 + c*8) = vb;
            }
        }
        for (int kd = 0; kd < 3; ++kd) {
            int dp = d0 + dd + kd - 1;         // per-wave
            bool dok = (dp >= 0) && (dp < DDEP);
            for (int kw = 0; kw < 3; ++kw) {
                __syncthreads();               // prev tap's Aw reads done (also fences L/R stage)
                {
                    const u16* as = wa + (size_t)(kd*9 + kh*3 + kw)*8192;
                    #pragma unroll
                    for (int gq = 0; gq < 4; ++gq) {
                        int eb = (gq*256 + tid)*8;
                        int o = eb >> 7, ii = eb & 127;
                        *(u32x4*)(Aw + o*136 + ii) = *(const u32x4*)(as + eb);
                    }
                }
                __syncthreads();

                int laddr[5], raddr[5];
                bool val[5];
                #pragma unroll
                for (int nf = 0; nf < 5; ++nf) {
                    int wp = wcol + nf*16 + kw - 1;
                    bool vv = dok && (wp >= 0) && (wp < WW) && (wp >= dp);
                    val[nf]   = vv;
                    laddr[nf] = (vv ? wp : 0)*72;
                    raddr[nf] = (vv ? (wp - dp) : 0)*72;
                }
                #pragma unroll
                for (int ic = 0; ic < 4; ++ic) {
                    const int kcolA = ic*32 + 8*l4;
                    bf16x8 a0 = *(const bf16x8*)(Aw + ( 0 + l15)*136 + kcolA);
                    bf16x8 a1 = *(const bf16x8*)(Aw + (16 + l15)*136 + kcolA);
                    bf16x8 a2 = *(const bf16x8*)(Aw + (32 + l15)*136 + kcolA);
                    bf16x8 a3 = *(const bf16x8*)(Aw + (48 + l15)*136 + kcolA);
                    const int kin = (ic & 1)*32 + 8*l4;
                    #pragma unroll
                    for (int nf = 0; nf < 5; ++nf) {
                        const u16* bp = (ic < 2) ? (Lt + laddr[nf] + kin)
                                                 : (Rt + raddr[nf] + kin);
                        bf16x8 b = *(const bf16x8*)bp;
                        b = val[nf] ? b : bzero;
                        acc[0][nf] = __builtin_amdgcn_mfma_f32_16x16x32_bf16(a0, b, acc[0][nf], 0, 0, 0);
                        acc[1][nf] = __builtin_amdgcn_mfma_f32_16x16x32_bf16(a1, b, acc[1][nf], 0, 0, 0);
                        acc[2][nf] = __builtin_amdgcn_mfma_f32_16x16x32_bf16(a2, b, acc[2][nf], 0, 0, 0);
                        acc[3][nf] = __builtin_amdgcn_mfma_f32_16x16x32_bf16(a3, b, acc[3][nf], 0, 0, 0);
                    }
                }
            }
        }
    }

    __syncthreads();   // all waves done reading Lt/Rt/Aw before epilogue reuse
    u16* eps = sm + wv*5280;   // per-wave [80][66] bf16 transpose buffer
    float sc[4][4], sh[4][4];
    #pragma unroll
    for (int mf = 0; mf < 4; ++mf)
        #pragma unroll
        for (int r = 0; r < 4; ++r) {
            int o = mf*16 + 4*l4 + r;
            sc[mf][r] = bnc[o];
            sh[mf][r] = bnc[64 + o];
        }
    #pragma unroll
    for (int mf = 0; mf < 4; ++mf)
        #pragma unroll
        for (int nf = 0; nf < 5; ++nf)
            #pragma unroll
            for (int r = 0; r < 4; ++r) {
                float vv = acc[mf][nf][r]*sc[mf][r] + sh[mf][r];
                vv = vv > 0.f ? vv : 0.f;
                eps[(nf*16 + l15)*66 + mf*16 + 4*l4 + r] = f2bf(vv);
            }
    // store y2[d][h][c=o/8][w=160][8]
    const int dy = d0 + dd;
    u16* yb2 = yt + ((size_t)(dy*HH + h))*10240;
    #pragma unroll
    for (int k = 0; k < 40; ++k) {
        int flat = k*64 + l;
        int c   = flat / 320;          // o-chunk 0..7
        int rem = flat - c*320;
        int w   = rem >> 2;            // local w 0..79
        int pr  = (rem & 3)*2;         // o-pair within chunk
        u32 vv = *(const u32*)(eps + w*66 + c*8 + pr);
        *(u32*)(yb2 + (size_t)c*1280 + (wbase + w)*8 + pr) = vv;
    }
}

// ---------------------------------------------------------------------------
// conv3b: 3x3x3 conv on y2[d][h][c][w][8], bf16 MFMA, fp32 out + BN + ReLU.
// EXACT r11 version (proven, ~40us). Block = (h, d-pair), 4 waves. B from
// GLOBAL (256B-contiguous per 16-lane phase); LDS = weight slab only.
// grid (48,24), block 256.
// ---------------------------------------------------------------------------
__global__ __launch_bounds__(256) void k_conv3b(
    const u16* __restrict__ yt, const u16* __restrict__ wb,
    const float* __restrict__ bnc, float* __restrict__ outp)
{
    __shared__ u16 A2[12800];   // [64][200] (100 dw pitch, %32==4)

    const int h  = blockIdx.x;
    const int d0 = blockIdx.y*2;
    const int tid = threadIdx.x;
    const int l  = tid & 63;
    const int wv = tid >> 6;
    const int dd = wv >> 1;
    const int wbase = (wv & 1)*80;
    const int l15 = l & 15, l4 = l >> 4;
    const int wcol = wbase + l15;
    const bf16x8 bzero = {0,0,0,0,0,0,0,0};

    f32x4 acc[4][5];
    #pragma unroll
    for (int a = 0; a < 4; ++a)
        #pragma unroll
        for (int b = 0; b < 5; ++b)
            acc[a][b] = (f32x4){0.f,0.f,0.f,0.f};

    for (int kh = 0; kh < 3; ++kh) {
        int hp = h + kh - 1;
        if (hp < 0 || hp >= HH) continue;   // block-uniform
        for (int kd = 0; kd < 3; ++kd) {
            __syncthreads();                // prior A2 reads done
            {
                const u16* as = wb + (size_t)(kd*3 + kh)*12288;
                #pragma unroll
                for (int q = 0; q < 6; ++q) {
                    int idx = q*256 + tid;
                    int o = idx/24;
                    int cc = (idx - o*24)*8;
                    *(u32x4*)(A2 + o*200 + cc) = *(const u32x4*)(as + (size_t)idx*8);
                }
            }
            __syncthreads();

            const int dpw = d0 + dd + kd - 1;
            const bool dok = (dpw >= 0) && (dpw < DDEP);
            const int dc = min(max(dpw, 0), DDEP-1);
            const u16* yrow = yt + ((size_t)((dc*HH + hp)*8) + l4)*1280;
            for (int kw = 0; kw < 3; ++kw) {
                int gofs[5]; bool val[5];
                #pragma unroll
                for (int nf = 0; nf < 5; ++nf) {
                    int wp = wcol + nf*16 + kw - 1;
                    bool vv = dok && (wp >= 0) && (wp < WW);
                    val[nf]  = vv;
                    gofs[nf] = (vv ? wp : 0)*8;
                }
                #pragma unroll
                for (int ic = 0; ic < 2; ++ic) {
                    const int kcolA = kw*64 + ic*32 + 8*l4;
                    bf16x8 a0 = *(const bf16x8*)(A2 + ( 0 + l15)*200 + kcolA);
                    bf16x8 a1 = *(const bf16x8*)(A2 + (16 + l15)*200 + kcolA);
                    bf16x8 a2 = *(const bf16x8*)(A2 + (32 + l15)*200 + kcolA);
                    bf16x8 a3 = *(const bf16x8*)(A2 + (48 + l15)*200 + kcolA);
                    const u16* yc = yrow + ic*5120;
                    #pragma unroll
                    for (int nf = 0; nf < 5; ++nf) {
                        bf16x8 b = *(const bf16x8*)(yc + gofs[nf]);
                        b = val[nf] ? b : bzero;
                        acc[0][nf] = __builtin_amdgcn_mfma_f32_16x16x32_bf16(a0, b, acc[0][nf], 0, 0, 0);
                        acc[1][nf] = __builtin_amdgcn_mfma_f32_16x16x32_bf16(a1, b, acc[1][nf], 0, 0, 0);
                        acc[2][nf] = __builtin_amdgcn_mfma_f32_16x16x32_bf16(a2, b, acc[2][nf], 0, 0, 0);
                        acc[3][nf] = __builtin_amdgcn_mfma_f32_16x16x32_bf16(a3, b, acc[3][nf], 0, 0, 0);
                    }
                }
            }
        }
    }

    // epilogue: fp32 out[(o*48+d)*48*160 + h*160 + w], coalesced along w
    const int dout = d0 + dd;
    #pragma unroll
    for (int mf = 0; mf < 4; ++mf)
        #pragma unroll
        for (int r = 0; r < 4; ++r) {
            int o = mf*16 + 4*l4 + r;
            float s = bnc[128 + o], t = bnc[192 + o];
            size_t base = ((size_t)(o*DDEP + dout)*HH + h)*WW + wbase;
            #pragma unroll
            for (int nf = 0; nf < 5; ++nf) {
                float vv = acc[mf][nf][r]*s + t;
                outp[base + nf*16 + l15] = vv > 0.f ? vv : 0.f;
            }
        }
}

// ---------------------------------------------------------------------------
extern "C" void kernel_launch(void* const* d_in, const int* in_sizes, int n_in,
                              void* d_out, int out_size, void* d_ws, size_t ws_size,
                              hipStream_t stream)
{
    const float* left  = (const float*)d_in[0];
    const float* right = (const float*)d_in[1];
    const float* w1    = (const float*)d_in[2];
    const float* b1    = (const float*)d_in[3];
    const float* g1    = (const float*)d_in[4];
    const float* bb1   = (const float*)d_in[5];
    const float* m1    = (const float*)d_in[6];
    const float* v1    = (const float*)d_in[7];
    const float* c3a   = (const float*)d_in[8];
    const float* cb3a  = (const float*)d_in[9];
    const float* g3a   = (const float*)d_in[10];
    const float* b3a   = (const float*)d_in[11];
    const float* m3a   = (const float*)d_in[12];
    const float* v3a   = (const float*)d_in[13];
    const float* c3b   = (const float*)d_in[14];
    const float* cb3b  = (const float*)d_in[15];
    const float* g3b   = (const float*)d_in[16];
    const float* b3b   = (const float*)d_in[17];
    const float* m3b   = (const float*)d_in[18];
    const float* v3b   = (const float*)d_in[19];

    // workspace layout (bytes, all 16B-aligned):
    //   LRb2 bf16 [2][48][8][160][8]     : 1,966,080   (chunked conv1 output)
    //   wa   bf16 [27][64][128]          :   442,368
    //   wb   bf16 [9][64][192]           :   221,184
    //   bnc  f32  [256]                  :     1,024
    //   yt   bf16 [48][48][8][160][8]    : 47,185,920  (chunked y2 layout)
    // conv1 split-K partials (fp32, 62.9 MB) live in d_out (94 MB fp32),
    // which conv3b fully overwrites afterwards.
    char* ws = (char*)d_ws;
    u16*   LRb = (u16*)ws;
    u16*   wa  = (u16*)(ws + 1966080);
    u16*   wb  = (u16*)(ws + 1966080 + 442368);
    float* bnc = (float*)(ws + 1966080 + 442368 + 221184);
    u16*   yt  = (u16*)(ws + 1966080 + 442368 + 221184 + 1024);
    if (ws_size < 49816576) return;   // visible failure (all-zero out) rather than corruption

    float* P = (float*)d_out;         // [KSPL][2][7680][64] fp32 partials

    k_prep<<<dim3(1296), dim3(256), 0, stream>>>(
        c3a, c3b, cb3a, g3a, b3a, m3a, v3a, cb3b, g3b, b3b, m3b, v3b, wa, wb, bnc);
    k_conv1<<<dim3(120, 2, KSPL), dim3(256), 0, stream>>>(
        left, right, w1, P);
    k_conv1_reduce<<<dim3(960), dim3(256), 0, stream>>>(
        P, b1, g1, bb1, m1, v1, LRb);
    k_conv3a<<<dim3(48, 24), dim3(256), 0, stream>>>(LRb, wa, bnc, yt);
    k_conv3b<<<dim3(48, 24), dim3(256), 0, stream>>>(yt, wb, bnc, (float*)d_out);
}